// Round 2
// baseline (390.859 us; speedup 1.0000x reference)
//
#include <hip/hip_runtime.h>

// ---------- common helpers ----------
typedef __bf16 bf16x8 __attribute__((ext_vector_type(8)));
typedef float  f32x4  __attribute__((ext_vector_type(4)));

__device__ __forceinline__ float bfl(unsigned short s) {
    return __uint_as_float(((unsigned int)s) << 16);
}
__device__ __forceinline__ unsigned short f2bf(float f) {  // RNE
    unsigned int x = __float_as_uint(f);
    x += 0x7fffu + ((x >> 16) & 1u);
    return (unsigned short)(x >> 16);
}
__device__ __forceinline__ float silu_f(float x) {
    return x / (1.f + expf(-x));
}

// dims
#define BSZ   2
#define LSEQ  2048
#define DMODEL 1024
#define DI    2048
#define DS    16
#define NCH   64        // chunks
#define CL    32        // steps per chunk (LSEQ/NCH)

// ---------- LayerNorm (f32 in -> bf16 out) ----------
__global__ __launch_bounds__(256) void ln_kernel(
    const float* __restrict__ x,
    const float* __restrict__ g,
    const float* __restrict__ b,
    unsigned short* __restrict__ xn)
{
    const int row = blockIdx.x;
    const int tid = threadIdx.x;
    const int lane = tid & 63, wv = tid >> 6;
    const float* xp = x + (size_t)row * DMODEL;

    float4 v = ((const float4*)xp)[tid];
    float s = v.x + v.y + v.z + v.w;
    float q = v.x*v.x + v.y*v.y + v.z*v.z + v.w*v.w;
    #pragma unroll
    for (int o = 32; o > 0; o >>= 1) {
        s += __shfl_down(s, o);
        q += __shfl_down(q, o);
    }
    __shared__ float ss[4], sq[4];
    if (lane == 0) { ss[wv] = s; sq[wv] = q; }
    __syncthreads();
    s = ss[0] + ss[1] + ss[2] + ss[3];
    q = sq[0] + sq[1] + sq[2] + sq[3];
    const float mu  = s * (1.f / DMODEL);
    const float var = q * (1.f / DMODEL) - mu * mu;
    const float rs  = rsqrtf(var + 1e-5f);

    float4 gv = ((const float4*)g)[tid];
    float4 bv = ((const float4*)b)[tid];
    ushort4 o;
    o.x = f2bf((v.x - mu) * rs * gv.x + bv.x);
    o.y = f2bf((v.y - mu) * rs * gv.y + bv.y);
    o.z = f2bf((v.z - mu) * rs * gv.z + bv.z);
    o.w = f2bf((v.w - mu) * rs * gv.w + bv.w);
    ((ushort4*)(xn + (size_t)row * DMODEL))[tid] = o;
}

// ---------- staging helper: 8 contiguous elems -> 8 bf16 in LDS ----------
template<bool F32>
__device__ __forceinline__ void stage8(unsigned short* dst, const void* src) {
    if constexpr (F32) {
        const float* s = (const float*)src;
        float4 a = *(const float4*)s;
        float4 b = *(const float4*)(s + 4);
        dst[0] = f2bf(a.x); dst[1] = f2bf(a.y); dst[2] = f2bf(a.z); dst[3] = f2bf(a.w);
        dst[4] = f2bf(b.x); dst[5] = f2bf(b.y); dst[6] = f2bf(b.z); dst[7] = f2bf(b.w);
    } else {
        *(uint4*)dst = *(const uint4*)src;
    }
}

// ---------- GEMM: C[M,N] = A[M,K] * B[N,K]^T (K-major operands, bf16 MFMA) ----------
// AF32/BF32: source dtype of A/B (converted to bf16 during LDS staging)
// EPI 0: store bf16 to Cout (ldc)
// EPI 1: store f32 to Cout (ldc) + bf16 copy of cols<64 into aux0 (ld 64)
// EPI 2: v = softplus(v + f32 aux0[col]); store f32
// EPI 3: v += f32 aux0[row*ldc+col]; store f32 (residual add)
template<int BM, int BN, int BK, int EPI, bool AF32, bool BF32>
__global__ __launch_bounds__(256) void gemm_bt(
    const void* __restrict__ A,
    const void* __restrict__ Bw,
    void* __restrict__ Cout,
    const void* __restrict__ aux0,
    int K, int ldc)
{
    constexpr int LDP = BK + 8;
    constexpr int FM = BM / 32;
    constexpr int FN = BN / 32;
    __shared__ unsigned short As[BM * LDP];
    __shared__ unsigned short Bs[BN * LDP];

    const int tid  = threadIdx.x;
    const int lane = tid & 63;
    const int wv   = tid >> 6;
    const int wm   = (wv >> 1) * (BM / 2);
    const int wn   = (wv & 1)  * (BN / 2);

    f32x4 acc[FM][FN];
    f32x4 z4 = {0.f, 0.f, 0.f, 0.f};
    #pragma unroll
    for (int i = 0; i < FM; ++i)
        #pragma unroll
        for (int j = 0; j < FN; ++j) acc[i][j] = z4;

    const int r0 = tid >> 3;
    const int c0 = (tid & 7) * 8;
    const size_t am0 = (size_t)blockIdx.x * BM;
    const size_t bn0 = (size_t)blockIdx.y * BN;

    for (int k0 = 0; k0 < K; k0 += BK) {
        __syncthreads();
        #pragma unroll
        for (int p = 0; p < BM / 32; ++p) {
            int r = r0 + p * 32;
            const size_t off = (am0 + r) * (size_t)K + k0 + c0;
            stage8<AF32>(&As[r * LDP + c0],
                         AF32 ? (const void*)((const float*)A + off)
                              : (const void*)((const unsigned short*)A + off));
        }
        #pragma unroll
        for (int p = 0; p < BN / 32; ++p) {
            int r = r0 + p * 32;
            const size_t off = (bn0 + r) * (size_t)K + k0 + c0;
            stage8<BF32>(&Bs[r * LDP + c0],
                         BF32 ? (const void*)((const float*)Bw + off)
                              : (const void*)((const unsigned short*)Bw + off));
        }
        __syncthreads();
        const int lr = lane & 15, lk = (lane >> 4) * 8;
        #pragma unroll
        for (int ks = 0; ks < BK / 32; ++ks) {
            bf16x8 af[FM], bfr[FN];
            #pragma unroll
            for (int fm = 0; fm < FM; ++fm)
                af[fm] = *(const bf16x8*)&As[(wm + fm * 16 + lr) * LDP + ks * 32 + lk];
            #pragma unroll
            for (int fn = 0; fn < FN; ++fn)
                bfr[fn] = *(const bf16x8*)&Bs[(wn + fn * 16 + lr) * LDP + ks * 32 + lk];
            #pragma unroll
            for (int fm = 0; fm < FM; ++fm)
                #pragma unroll
                for (int fn = 0; fn < FN; ++fn)
                    acc[fm][fn] = __builtin_amdgcn_mfma_f32_16x16x32_bf16(
                        af[fm], bfr[fn], acc[fm][fn], 0, 0, 0);
        }
    }

    const int er = (lane >> 4) * 4;
    const int ec = lane & 15;
    #pragma unroll
    for (int fm = 0; fm < FM; ++fm) {
        #pragma unroll
        for (int fn = 0; fn < FN; ++fn) {
            const size_t col = bn0 + wn + fn * 16 + ec;
            #pragma unroll
            for (int r = 0; r < 4; ++r) {
                const size_t row = am0 + wm + fm * 16 + er + r;
                float v = acc[fm][fn][r];
                if constexpr (EPI == 0) {
                    ((unsigned short*)Cout)[row * ldc + col] = f2bf(v);
                } else if constexpr (EPI == 1) {
                    ((float*)Cout)[row * ldc + col] = v;
                    if ((int)col < 64)
                        ((unsigned short*)aux0)[row * 64 + col] = f2bf(v);
                } else if constexpr (EPI == 2) {
                    float t = v + ((const float*)aux0)[col];
                    float sp = fmaxf(t, 0.f) + log1pf(expf(-fabsf(t)));
                    ((float*)Cout)[row * ldc + col] = sp;
                } else {
                    float t = v + ((const float*)aux0)[row * ldc + col];
                    ((float*)Cout)[row * ldc + col] = t;
                }
            }
        }
    }
}

// ---------- causal depthwise conv (window 4) + bias + SiLU ----------
__global__ __launch_bounds__(256) void conv_silu(
    const unsigned short* __restrict__ xz,     // (B*L, 2*DI) bf16, u = cols [0,DI)
    const float* __restrict__ convw,           // (DI,4) f32
    const float* __restrict__ convb,           // (DI,) f32
    unsigned short* __restrict__ u_c)          // (B*L, DI) bf16
{
    const size_t i = (size_t)blockIdx.x * 256 + threadIdx.x;
    if (i >= (size_t)BSZ * LSEQ * DI) return;
    const int d = (int)(i & (DI - 1));
    const size_t bl = i >> 11;            // b*L + l
    const int l = (int)(bl & (LSEQ - 1));
    const int b = (int)(bl >> 11);

    float4 wv = *(const float4*)&convw[d * 4];
    float acc = convb[d];
    const size_t rowbase = (size_t)(b * LSEQ) * (2 * DI) + d;
    if (l >= 3) acc += bfl(xz[rowbase + (size_t)(l - 3) * (2 * DI)]) * wv.x;
    if (l >= 2) acc += bfl(xz[rowbase + (size_t)(l - 2) * (2 * DI)]) * wv.y;
    if (l >= 1) acc += bfl(xz[rowbase + (size_t)(l - 1) * (2 * DI)]) * wv.z;
    acc += bfl(xz[rowbase + (size_t)l * (2 * DI)]) * wv.w;
    u_c[i] = f2bf(silu_f(acc));
}

// ---------- selective scan, pass 1: per-chunk local scan (h_in = 0) ----------
__global__ __launch_bounds__(256) void scan1(
    const float* __restrict__ dt,           // (B*L, DI) f32
    const unsigned short* __restrict__ u_c, // (B*L, DI) bf16
    const float* __restrict__ x_dbl,        // (B*L, 96) f32; B = cols 64..79
    const float* __restrict__ A_log,        // (DI,16) f32
    float* __restrict__ chunk_h,            // [b][c][d][16] f32
    float* __restrict__ Ssum)               // [b][c][d] f32
{
    const int d = blockIdx.x * 256 + threadIdx.x;
    const int b = blockIdx.y, c = blockIdx.z;
    const int tid = threadIdx.x;

    __shared__ float sB[CL][DS];
    if (tid < 128) {
        int s = tid >> 2, j = (tid & 3) * 4;
        *(float4*)&sB[s][j] =
            *(const float4*)&x_dbl[(size_t)(b * LSEQ + c * CL + s) * 96 + 64 + j];
    }

    float An[DS];
    #pragma unroll
    for (int i = 0; i < 4; ++i) {
        float4 a = *(const float4*)&A_log[(size_t)d * DS + i * 4];
        An[4*i+0] = -expf(a.x); An[4*i+1] = -expf(a.y);
        An[4*i+2] = -expf(a.z); An[4*i+3] = -expf(a.w);
    }
    __syncthreads();

    float h[DS];
    #pragma unroll
    for (int n = 0; n < DS; ++n) h[n] = 0.f;
    float S = 0.f;
    const size_t base = (size_t)(b * LSEQ + c * CL) * DI + d;
    for (int s = 0; s < CL; ++s) {
        float dtt = dt[base + (size_t)s * DI];
        float ut  = bfl(u_c[base + (size_t)s * DI]);
        S += dtt;
        float dtu = dtt * ut;
        #pragma unroll
        for (int n = 0; n < DS; ++n) {
            float dA = expf(dtt * An[n]);
            h[n] = dA * h[n] + dtu * sB[s][n];
        }
    }
    const size_t co = ((size_t)((b * NCH + c) * DI) + d) * DS;
    #pragma unroll
    for (int n = 0; n < DS; ++n) chunk_h[co + n] = h[n];
    Ssum[(size_t)(b * NCH + c) * DI + d] = S;
}

// ---------- scan pass 2: combine chunks; overwrite chunk_h with per-chunk h_in ----------
__global__ __launch_bounds__(256) void scan2(
    float* __restrict__ chunk_h,       // in: local ends; out: chunk start states
    const float* __restrict__ Ssum,
    const float* __restrict__ A_log)
{
    const int gid = blockIdx.x * 256 + threadIdx.x;   // (b,d,n)
    const int b = gid >> 15;
    const int rem = gid & 32767;
    const int d = rem >> 4;
    const int n = rem & 15;
    const float A = -expf(A_log[(size_t)d * DS + n]);
    float H = 0.f;
    for (int c = 0; c < NCH; ++c) {
        const size_t idx = ((size_t)((b * NCH + c) * DI) + d) * DS + n;
        float hl = chunk_h[idx];
        float S  = Ssum[(size_t)(b * NCH + c) * DI + d];
        chunk_h[idx] = H;                 // start state for chunk c
        H = expf(A * S) * H + hl;
    }
}

// ---------- scan pass 3: full scan with h_in + y = (h.C + D*u) * silu(z) ----------
__global__ __launch_bounds__(256) void scan3(
    const float* __restrict__ dt,
    const unsigned short* __restrict__ u_c,
    const float* __restrict__ x_dbl,          // B = 64..79, C = 80..95
    const float* __restrict__ A_log,
    const float* __restrict__ Hstart,         // = chunk_h after pass 2
    const float* __restrict__ Dvec,           // (DI,) f32
    const unsigned short* __restrict__ xz,    // z = cols [DI, 2*DI) bf16
    unsigned short* __restrict__ yb)          // (B*L, DI) bf16
{
    const int d = blockIdx.x * 256 + threadIdx.x;
    const int b = blockIdx.y, c = blockIdx.z;
    const int tid = threadIdx.x;

    __shared__ float sBC[CL][32];
    {
        int s = tid >> 3, j = (tid & 7) * 4;
        *(float4*)&sBC[s][j] =
            *(const float4*)&x_dbl[(size_t)(b * LSEQ + c * CL + s) * 96 + 64 + j];
    }

    float An[DS];
    #pragma unroll
    for (int i = 0; i < 4; ++i) {
        float4 a = *(const float4*)&A_log[(size_t)d * DS + i * 4];
        An[4*i+0] = -expf(a.x); An[4*i+1] = -expf(a.y);
        An[4*i+2] = -expf(a.z); An[4*i+3] = -expf(a.w);
    }
    const float Dd = Dvec[d];
    float h[DS];
    const size_t co = ((size_t)((b * NCH + c) * DI) + d) * DS;
    #pragma unroll
    for (int n = 0; n < DS; ++n) h[n] = Hstart[co + n];
    __syncthreads();

    const size_t base  = (size_t)(b * LSEQ + c * CL) * DI + d;
    const size_t zbase = (size_t)(b * LSEQ + c * CL) * (2 * DI) + DI + d;
    for (int s = 0; s < CL; ++s) {
        float dtt = dt[base + (size_t)s * DI];
        float ut  = bfl(u_c[base + (size_t)s * DI]);
        float dtu = dtt * ut;
        float a0 = 0.f, a1 = 0.f;
        #pragma unroll
        for (int n = 0; n < DS; ++n) {
            float dA = expf(dtt * An[n]);
            h[n] = dA * h[n] + dtu * sBC[s][n];
            if (n & 1) a1 += h[n] * sBC[s][16 + n];
            else       a0 += h[n] * sBC[s][16 + n];
        }
        float y = a0 + a1 + Dd * ut;
        float z = bfl(xz[zbase + (size_t)s * (2 * DI)]);
        yb[base + (size_t)s * DI] = f2bf(y * silu_f(z));
    }
}

// ---------- host launcher ----------
extern "C" void kernel_launch(void* const* d_in, const int* in_sizes, int n_in,
                              void* d_out, int out_size, void* d_ws, size_t ws_size,
                              hipStream_t stream) {
    const float* x      = (const float*)d_in[0];
    const float* ln_g   = (const float*)d_in[1];
    const float* ln_b   = (const float*)d_in[2];
    const float* W_in   = (const float*)d_in[3];
    const float* conv_w = (const float*)d_in[4];
    const float* conv_b = (const float*)d_in[5];
    const float* W_xp   = (const float*)d_in[6];
    const float* W_dt   = (const float*)d_in[7];
    const float* b_dt   = (const float*)d_in[8];
    const float* A_log  = (const float*)d_in[9];
    const float* Dv     = (const float*)d_in[10];
    const float* W_out  = (const float*)d_in[11];
    float* out = (float*)d_out;

    char* w = (char*)d_ws;
    unsigned short* xn     = (unsigned short*)(w + 0);           //  8,388,608
    unsigned short* xz     = (unsigned short*)(w + 8388608);     // 33,554,432
    unsigned short* u_c    = (unsigned short*)(w + 41943040);    // 16,777,216
    float*          x_dbl  = (float*)         (w + 58720256);    //  1,572,864
    unsigned short* dtlow  = (unsigned short*)(w + 60293120);    //    524,288
    float*          dtb    = (float*)         (w + 60817408);    // 33,554,432
    float*          chunkh = (float*)         (w + 94371840);    // 16,777,216
    float*          Ssum   = (float*)         (w + 111149056);   //  1,048,576
    unsigned short* yb     = (unsigned short*)(w + 112197632);   // 16,777,216
    (void)in_sizes; (void)n_in; (void)out_size; (void)ws_size;

    const int MROWS = BSZ * LSEQ;  // 4096

    // 1. LayerNorm (f32 -> bf16)
    ln_kernel<<<MROWS, 256, 0, stream>>>(x, ln_g, ln_b, xn);
    // 2. xz = xn @ W_in^T  (4096x1024 @ 1024x4096) -> bf16
    gemm_bt<128, 128, 64, 0, false, true><<<dim3(32, 32), 256, 0, stream>>>(
        xn, W_in, xz, nullptr, DMODEL, 2 * DI);
    // 3. causal conv + SiLU -> bf16
    conv_silu<<<(MROWS * DI) / 256, 256, 0, stream>>>(xz, conv_w, conv_b, u_c);
    // 4. x_dbl = u_c @ W_xp^T  (4096x2048 @ 2048x96) -> f32 (+ bf16 dt-low copy)
    gemm_bt<64, 96, 64, 1, false, true><<<dim3(64, 1), 256, 0, stream>>>(
        u_c, W_xp, x_dbl, dtlow, DI, 96);
    // 5. dt = softplus(dtlow @ W_dt^T + b_dt)  (4096x64 @ 64x2048) -> f32
    gemm_bt<128, 128, 64, 2, false, true><<<dim3(32, 16), 256, 0, stream>>>(
        dtlow, W_dt, dtb, b_dt, 64, DI);
    // 6-8. chunked selective scan (+ D*u, * silu(z)) -> yb bf16
    scan1<<<dim3(DI / 256, BSZ, NCH), 256, 0, stream>>>(
        dtb, u_c, x_dbl, A_log, chunkh, Ssum);
    scan2<<<(BSZ * DI * DS) / 256, 256, 0, stream>>>(chunkh, Ssum, A_log);
    scan3<<<dim3(DI / 256, BSZ, NCH), 256, 0, stream>>>(
        dtb, u_c, x_dbl, A_log, chunkh, Dv, xz, yb);
    // 9. out = yb @ W_out^T + x  (4096x2048 @ 2048x1024) -> f32
    gemm_bt<128, 128, 64, 3, false, true><<<dim3(32, 8), 256, 0, stream>>>(
        yb, W_out, out, x, DI, DMODEL);
}

// Round 3
// 251.555 us; speedup vs baseline: 1.5538x; 1.5538x over previous
//
#include <hip/hip_runtime.h>

// ---------- common helpers ----------
typedef __bf16 bf16x8 __attribute__((ext_vector_type(8)));
typedef float  f32x4  __attribute__((ext_vector_type(4)));

#define LOG2E 1.44269504088896f

__device__ __forceinline__ float bfl(unsigned short s) {
    return __uint_as_float(((unsigned int)s) << 16);
}
__device__ __forceinline__ unsigned short f2bf(float f) {  // RNE
    unsigned int x = __float_as_uint(f);
    x += 0x7fffu + ((x >> 16) & 1u);
    return (unsigned short)(x >> 16);
}
__device__ __forceinline__ float fexp2(float x) { return __builtin_amdgcn_exp2f(x); }
__device__ __forceinline__ float fexp(float x)  { return __builtin_amdgcn_exp2f(x * LOG2E); }
__device__ __forceinline__ float frcp(float x)  { return __builtin_amdgcn_rcpf(x); }
__device__ __forceinline__ float silu_f(float x) {
    // x / (1 + e^-x); exp2 overflow/underflow gives correct limits
    return x * frcp(1.f + fexp2(-x * LOG2E));
}

// dims
#define BSZ   2
#define LSEQ  2048
#define DMODEL 1024
#define DI    2048
#define DS    16
#define NCH   64        // chunks
#define CL    32        // steps per chunk (LSEQ/NCH)

// ---------- f32 -> bf16 weight conversion (4 concatenated segments) ----------
#define WI_N   4194304          // 2*DI*DMODEL
#define WXP_N  196608           // 96*DI
#define WDT_N  131072           // DI*64
#define WOUT_N 2097152          // DMODEL*DI
#define WSEG1  (WI_N)
#define WSEG2  (WI_N + WXP_N)
#define WSEG3  (WI_N + WXP_N + WDT_N)
#define WTOT   (WI_N + WXP_N + WDT_N + WOUT_N)   // 6,619,136

__global__ __launch_bounds__(256) void cvt_weights(
    const float* __restrict__ w0, const float* __restrict__ w1,
    const float* __restrict__ w2, const float* __restrict__ w3,
    unsigned short* __restrict__ dst)
{
    const size_t e0 = ((size_t)blockIdx.x * 256 + threadIdx.x) * 8;
    if (e0 >= WTOT) return;
    const float* src;
    size_t off;
    if      (e0 < WSEG1) { src = w0; off = e0; }
    else if (e0 < WSEG2) { src = w1; off = e0 - WSEG1; }
    else if (e0 < WSEG3) { src = w2; off = e0 - WSEG2; }
    else                 { src = w3; off = e0 - WSEG3; }
    float4 a = *(const float4*)(src + off);
    float4 b = *(const float4*)(src + off + 4);
    ushort4 lo, hi;
    lo.x = f2bf(a.x); lo.y = f2bf(a.y); lo.z = f2bf(a.z); lo.w = f2bf(a.w);
    hi.x = f2bf(b.x); hi.y = f2bf(b.y); hi.z = f2bf(b.z); hi.w = f2bf(b.w);
    *(ushort4*)(dst + e0) = lo;
    *(ushort4*)(dst + e0 + 4) = hi;
}

// ---------- LayerNorm (f32 in -> bf16 out) ----------
__global__ __launch_bounds__(256) void ln_kernel(
    const float* __restrict__ x,
    const float* __restrict__ g,
    const float* __restrict__ b,
    unsigned short* __restrict__ xn)
{
    const int row = blockIdx.x;
    const int tid = threadIdx.x;
    const int lane = tid & 63, wv = tid >> 6;
    const float* xp = x + (size_t)row * DMODEL;

    float4 v = ((const float4*)xp)[tid];
    float s = v.x + v.y + v.z + v.w;
    float q = v.x*v.x + v.y*v.y + v.z*v.z + v.w*v.w;
    #pragma unroll
    for (int o = 32; o > 0; o >>= 1) {
        s += __shfl_down(s, o);
        q += __shfl_down(q, o);
    }
    __shared__ float ss[4], sq[4];
    if (lane == 0) { ss[wv] = s; sq[wv] = q; }
    __syncthreads();
    s = ss[0] + ss[1] + ss[2] + ss[3];
    q = sq[0] + sq[1] + sq[2] + sq[3];
    const float mu  = s * (1.f / DMODEL);
    const float var = q * (1.f / DMODEL) - mu * mu;
    const float rs  = rsqrtf(var + 1e-5f);

    float4 gv = ((const float4*)g)[tid];
    float4 bv = ((const float4*)b)[tid];
    ushort4 o;
    o.x = f2bf((v.x - mu) * rs * gv.x + bv.x);
    o.y = f2bf((v.y - mu) * rs * gv.y + bv.y);
    o.z = f2bf((v.z - mu) * rs * gv.z + bv.z);
    o.w = f2bf((v.w - mu) * rs * gv.w + bv.w);
    ((ushort4*)(xn + (size_t)row * DMODEL))[tid] = o;
}

// ---------- GEMM: C[M,N] = A[M,K] * B[N,K]^T (bf16 K-major operands) ----------
// EPI 0: store bf16 to Cout (ldc)
// EPI 1: store f32 to Cout (ldc) + bf16 copy of cols<64 into aux0 (ld 64)
// EPI 2: v = softplus(v + f32 aux0[col]); store f32
// EPI 3: v += f32 aux0[row*ldc+col]; store f32 (residual add)
template<int BM, int BN, int BK, int EPI>
__global__ __launch_bounds__(256) void gemm_bt(
    const unsigned short* __restrict__ A,
    const unsigned short* __restrict__ Bw,
    void* __restrict__ Cout,
    const void* __restrict__ aux0,
    int K, int ldc)
{
    constexpr int LDP = BK + 8;
    constexpr int FM = BM / 32;
    constexpr int FN = BN / 32;
    __shared__ unsigned short As[BM * LDP];
    __shared__ unsigned short Bs[BN * LDP];

    const int tid  = threadIdx.x;
    const int lane = tid & 63;
    const int wv   = tid >> 6;
    const int wm   = (wv >> 1) * (BM / 2);
    const int wn   = (wv & 1)  * (BN / 2);

    f32x4 acc[FM][FN];
    f32x4 z4 = {0.f, 0.f, 0.f, 0.f};
    #pragma unroll
    for (int i = 0; i < FM; ++i)
        #pragma unroll
        for (int j = 0; j < FN; ++j) acc[i][j] = z4;

    const int r0 = tid >> 3;
    const int c0 = (tid & 7) * 8;
    const size_t am0 = (size_t)blockIdx.x * BM;
    const size_t bn0 = (size_t)blockIdx.y * BN;

    for (int k0 = 0; k0 < K; k0 += BK) {
        __syncthreads();
        #pragma unroll
        for (int p = 0; p < BM / 32; ++p) {
            int r = r0 + p * 32;
            *(uint4*)&As[r * LDP + c0] = *(const uint4*)&A[(am0 + r) * (size_t)K + k0 + c0];
        }
        #pragma unroll
        for (int p = 0; p < BN / 32; ++p) {
            int r = r0 + p * 32;
            *(uint4*)&Bs[r * LDP + c0] = *(const uint4*)&Bw[(bn0 + r) * (size_t)K + k0 + c0];
        }
        __syncthreads();
        const int lr = lane & 15, lk = (lane >> 4) * 8;
        #pragma unroll
        for (int ks = 0; ks < BK / 32; ++ks) {
            bf16x8 af[FM], bfr[FN];
            #pragma unroll
            for (int fm = 0; fm < FM; ++fm)
                af[fm] = *(const bf16x8*)&As[(wm + fm * 16 + lr) * LDP + ks * 32 + lk];
            #pragma unroll
            for (int fn = 0; fn < FN; ++fn)
                bfr[fn] = *(const bf16x8*)&Bs[(wn + fn * 16 + lr) * LDP + ks * 32 + lk];
            #pragma unroll
            for (int fm = 0; fm < FM; ++fm)
                #pragma unroll
                for (int fn = 0; fn < FN; ++fn)
                    acc[fm][fn] = __builtin_amdgcn_mfma_f32_16x16x32_bf16(
                        af[fm], bfr[fn], acc[fm][fn], 0, 0, 0);
        }
    }

    const int er = (lane >> 4) * 4;
    const int ec = lane & 15;
    #pragma unroll
    for (int fm = 0; fm < FM; ++fm) {
        #pragma unroll
        for (int fn = 0; fn < FN; ++fn) {
            const size_t col = bn0 + wn + fn * 16 + ec;
            #pragma unroll
            for (int r = 0; r < 4; ++r) {
                const size_t row = am0 + wm + fm * 16 + er + r;
                float v = acc[fm][fn][r];
                if constexpr (EPI == 0) {
                    ((unsigned short*)Cout)[row * ldc + col] = f2bf(v);
                } else if constexpr (EPI == 1) {
                    ((float*)Cout)[row * ldc + col] = v;
                    if ((int)col < 64)
                        ((unsigned short*)aux0)[row * 64 + col] = f2bf(v);
                } else if constexpr (EPI == 2) {
                    float t = v + ((const float*)aux0)[col];
                    float e = fexp2(t * LOG2E);
                    float sp = 0.69314718056f * __builtin_amdgcn_logf(1.f + e);
                    if (t > 20.f) sp = t;
                    ((float*)Cout)[row * ldc + col] = sp;
                } else {
                    float t = v + ((const float*)aux0)[row * ldc + col];
                    ((float*)Cout)[row * ldc + col] = t;
                }
            }
        }
    }
}

// ---------- causal depthwise conv (window 4) + bias + SiLU ----------
__global__ __launch_bounds__(256) void conv_silu(
    const unsigned short* __restrict__ xz,     // (B*L, 2*DI) bf16, u = cols [0,DI)
    const float* __restrict__ convw,           // (DI,4) f32
    const float* __restrict__ convb,           // (DI,) f32
    unsigned short* __restrict__ u_c)          // (B*L, DI) bf16
{
    const size_t i = (size_t)blockIdx.x * 256 + threadIdx.x;
    if (i >= (size_t)BSZ * LSEQ * DI) return;
    const int d = (int)(i & (DI - 1));
    const size_t bl = i >> 11;            // b*L + l
    const int l = (int)(bl & (LSEQ - 1));
    const int b = (int)(bl >> 11);

    float4 wv = *(const float4*)&convw[d * 4];
    float acc = convb[d];
    const size_t rowbase = (size_t)(b * LSEQ) * (2 * DI) + d;
    if (l >= 3) acc += bfl(xz[rowbase + (size_t)(l - 3) * (2 * DI)]) * wv.x;
    if (l >= 2) acc += bfl(xz[rowbase + (size_t)(l - 2) * (2 * DI)]) * wv.y;
    if (l >= 1) acc += bfl(xz[rowbase + (size_t)(l - 1) * (2 * DI)]) * wv.z;
    acc += bfl(xz[rowbase + (size_t)l * (2 * DI)]) * wv.w;
    u_c[i] = f2bf(silu_f(acc));
}

// ---------- A-row load: An2[n] = -exp(A_log[d][n]) * log2(e); fast = broadcast S4D ----------
__device__ __forceinline__ bool load_A(const float* __restrict__ A_log, int d, float* An2) {
    bool fast = true;
    #pragma unroll
    for (int i = 0; i < 4; ++i) {
        float4 a = *(const float4*)&A_log[(size_t)d * DS + i * 4];
        float e0 = fexp(a.x), e1 = fexp(a.y), e2 = fexp(a.z), e3 = fexp(a.w);
        fast = fast && fabsf(e0 - (4*i+1)) < 1e-3f * (4*i+1)
                    && fabsf(e1 - (4*i+2)) < 1e-3f * (4*i+2)
                    && fabsf(e2 - (4*i+3)) < 1e-3f * (4*i+3)
                    && fabsf(e3 - (4*i+4)) < 1e-3f * (4*i+4);
        An2[4*i+0] = -e0 * LOG2E; An2[4*i+1] = -e1 * LOG2E;
        An2[4*i+2] = -e2 * LOG2E; An2[4*i+3] = -e3 * LOG2E;
    }
    return fast;
}

// ---------- selective scan, pass 1: per-chunk local scan (h_in = 0) ----------
__global__ __launch_bounds__(256) void scan1(
    const float* __restrict__ dt,           // (B*L, DI) f32
    const unsigned short* __restrict__ u_c, // (B*L, DI) bf16
    const float* __restrict__ x_dbl,        // (B*L, 96) f32; B = cols 64..79
    const float* __restrict__ A_log,        // (DI,16) f32
    float* __restrict__ chunk_h,            // [b][c][d][16] f32
    float* __restrict__ Ssum)               // [b][c][d] f32
{
    const int d = blockIdx.x * 256 + threadIdx.x;
    const int b = blockIdx.y, c = blockIdx.z;
    const int tid = threadIdx.x;

    __shared__ float sB[CL][DS];
    if (tid < 128) {
        int s = tid >> 2, j = (tid & 3) * 4;
        *(float4*)&sB[s][j] =
            *(const float4*)&x_dbl[(size_t)(b * LSEQ + c * CL + s) * 96 + 64 + j];
    }

    float An2[DS];
    const bool fast = load_A(A_log, d, An2);
    __syncthreads();

    float h[DS];
    #pragma unroll
    for (int n = 0; n < DS; ++n) h[n] = 0.f;
    float S = 0.f;
    const size_t base = (size_t)(b * LSEQ + c * CL) * DI + d;
    if (fast) {
        for (int s = 0; s < CL; ++s) {
            float dtt = dt[base + (size_t)s * DI];
            float ut  = bfl(u_c[base + (size_t)s * DI]);
            S += dtt;
            float dtu = dtt * ut;
            float e1 = fexp2(-dtt * LOG2E);   // exp(-dt); dA[n] = e1^(n+1)
            float p = 1.f;
            #pragma unroll
            for (int n = 0; n < DS; ++n) {
                p *= e1;
                h[n] = p * h[n] + dtu * sB[s][n];
            }
        }
    } else {
        for (int s = 0; s < CL; ++s) {
            float dtt = dt[base + (size_t)s * DI];
            float ut  = bfl(u_c[base + (size_t)s * DI]);
            S += dtt;
            float dtu = dtt * ut;
            #pragma unroll
            for (int n = 0; n < DS; ++n) {
                float dA = fexp2(dtt * An2[n]);
                h[n] = dA * h[n] + dtu * sB[s][n];
            }
        }
    }
    const size_t co = ((size_t)((b * NCH + c) * DI) + d) * DS;
    #pragma unroll
    for (int n = 0; n < DS; ++n) chunk_h[co + n] = h[n];
    Ssum[(size_t)(b * NCH + c) * DI + d] = S;
}

// ---------- scan pass 2: combine chunks; overwrite chunk_h with per-chunk h_in ----------
__global__ __launch_bounds__(256) void scan2(
    float* __restrict__ chunk_h,       // in: local ends; out: chunk start states
    const float* __restrict__ Ssum,
    const float* __restrict__ A_log)
{
    const int gid = blockIdx.x * 256 + threadIdx.x;   // (b,d,n)
    const int b = gid >> 15;
    const int rem = gid & 32767;
    const int d = rem >> 4;
    const int n = rem & 15;
    const float A2 = -fexp(A_log[(size_t)d * DS + n]) * LOG2E;
    float H = 0.f;
    for (int c = 0; c < NCH; ++c) {
        const size_t idx = ((size_t)((b * NCH + c) * DI) + d) * DS + n;
        float hl = chunk_h[idx];
        float S  = Ssum[(size_t)(b * NCH + c) * DI + d];
        chunk_h[idx] = H;                 // start state for chunk c
        H = fexp2(A2 * S) * H + hl;
    }
}

// ---------- scan pass 3: full scan with h_in + y = (h.C + D*u) * silu(z) ----------
__global__ __launch_bounds__(256) void scan3(
    const float* __restrict__ dt,
    const unsigned short* __restrict__ u_c,
    const float* __restrict__ x_dbl,          // B = 64..79, C = 80..95
    const float* __restrict__ A_log,
    const float* __restrict__ Hstart,         // = chunk_h after pass 2
    const float* __restrict__ Dvec,           // (DI,) f32
    const unsigned short* __restrict__ xz,    // z = cols [DI, 2*DI) bf16
    unsigned short* __restrict__ yb)          // (B*L, DI) bf16
{
    const int d = blockIdx.x * 256 + threadIdx.x;
    const int b = blockIdx.y, c = blockIdx.z;
    const int tid = threadIdx.x;

    __shared__ float sBC[CL][32];
    {
        int s = tid >> 3, j = (tid & 7) * 4;
        *(float4*)&sBC[s][j] =
            *(const float4*)&x_dbl[(size_t)(b * LSEQ + c * CL + s) * 96 + 64 + j];
    }

    float An2[DS];
    const bool fast = load_A(A_log, d, An2);
    const float Dd = Dvec[d];
    float h[DS];
    const size_t co = ((size_t)((b * NCH + c) * DI) + d) * DS;
    #pragma unroll
    for (int n = 0; n < DS; ++n) h[n] = Hstart[co + n];
    __syncthreads();

    const size_t base  = (size_t)(b * LSEQ + c * CL) * DI + d;
    const size_t zbase = (size_t)(b * LSEQ + c * CL) * (2 * DI) + DI + d;
    if (fast) {
        for (int s = 0; s < CL; ++s) {
            float dtt = dt[base + (size_t)s * DI];
            float ut  = bfl(u_c[base + (size_t)s * DI]);
            float dtu = dtt * ut;
            float e1 = fexp2(-dtt * LOG2E);
            float p = 1.f;
            float a0 = 0.f, a1 = 0.f;
            #pragma unroll
            for (int n = 0; n < DS; ++n) {
                p *= e1;
                h[n] = p * h[n] + dtu * sBC[s][n];
                if (n & 1) a1 += h[n] * sBC[s][16 + n];
                else       a0 += h[n] * sBC[s][16 + n];
            }
            float y = a0 + a1 + Dd * ut;
            float z = bfl(xz[zbase + (size_t)s * (2 * DI)]);
            yb[base + (size_t)s * DI] = f2bf(y * silu_f(z));
        }
    } else {
        for (int s = 0; s < CL; ++s) {
            float dtt = dt[base + (size_t)s * DI];
            float ut  = bfl(u_c[base + (size_t)s * DI]);
            float dtu = dtt * ut;
            float a0 = 0.f, a1 = 0.f;
            #pragma unroll
            for (int n = 0; n < DS; ++n) {
                float dA = fexp2(dtt * An2[n]);
                h[n] = dA * h[n] + dtu * sBC[s][n];
                if (n & 1) a1 += h[n] * sBC[s][16 + n];
                else       a0 += h[n] * sBC[s][16 + n];
            }
            float y = a0 + a1 + Dd * ut;
            float z = bfl(xz[zbase + (size_t)s * (2 * DI)]);
            yb[base + (size_t)s * DI] = f2bf(y * silu_f(z));
        }
    }
}

// ---------- host launcher ----------
extern "C" void kernel_launch(void* const* d_in, const int* in_sizes, int n_in,
                              void* d_out, int out_size, void* d_ws, size_t ws_size,
                              hipStream_t stream) {
    const float* x      = (const float*)d_in[0];
    const float* ln_g   = (const float*)d_in[1];
    const float* ln_b   = (const float*)d_in[2];
    const float* W_in   = (const float*)d_in[3];
    const float* conv_w = (const float*)d_in[4];
    const float* conv_b = (const float*)d_in[5];
    const float* W_xp   = (const float*)d_in[6];
    const float* W_dt   = (const float*)d_in[7];
    const float* b_dt   = (const float*)d_in[8];
    const float* A_log  = (const float*)d_in[9];
    const float* Dv     = (const float*)d_in[10];
    const float* W_out  = (const float*)d_in[11];
    float* out = (float*)d_out;

    char* w = (char*)d_ws;
    unsigned short* xn     = (unsigned short*)(w + 0);           //  8,388,608
    unsigned short* xz     = (unsigned short*)(w + 8388608);     // 33,554,432
    unsigned short* u_c    = (unsigned short*)(w + 41943040);    // 16,777,216
    float*          x_dbl  = (float*)         (w + 58720256);    //  1,572,864
    unsigned short* dtlow  = (unsigned short*)(w + 60293120);    //    524,288
    float*          dtb    = (float*)         (w + 60817408);    // 33,554,432
    float*          chunkh = (float*)         (w + 94371840);    // 16,777,216
    float*          Ssum   = (float*)         (w + 111149056);   //  1,048,576
    unsigned short* yb     = (unsigned short*)(w + 112197632);   // 16,777,216
    unsigned short* wbf    = (unsigned short*)(w + 128974848);   // 13,238,272 (end 142,213,120)
    unsigned short* Wi_bf   = wbf;
    unsigned short* Wxp_bf  = wbf + WSEG1;
    unsigned short* Wdt_bf  = wbf + WSEG2;
    unsigned short* Wout_bf = wbf + WSEG3;
    (void)in_sizes; (void)n_in; (void)out_size; (void)ws_size;

    const int MROWS = BSZ * LSEQ;  // 4096

    // 0. weights f32 -> bf16
    cvt_weights<<<(WTOT / 8 + 255) / 256, 256, 0, stream>>>(
        W_in, W_xp, W_dt, W_out, wbf);
    // 1. LayerNorm (f32 -> bf16)
    ln_kernel<<<MROWS, 256, 0, stream>>>(x, ln_g, ln_b, xn);
    // 2. xz = xn @ W_in^T  (4096x1024 @ 1024x4096) -> bf16
    gemm_bt<128, 128, 64, 0><<<dim3(32, 32), 256, 0, stream>>>(
        xn, Wi_bf, xz, nullptr, DMODEL, 2 * DI);
    // 3. causal conv + SiLU -> bf16
    conv_silu<<<(MROWS * DI) / 256, 256, 0, stream>>>(xz, conv_w, conv_b, u_c);
    // 4. x_dbl = u_c @ W_xp^T  (4096x2048 @ 2048x96) -> f32 (+ bf16 dt-low copy)
    gemm_bt<64, 96, 64, 1><<<dim3(64, 1), 256, 0, stream>>>(
        u_c, Wxp_bf, x_dbl, dtlow, DI, 96);
    // 5. dt = softplus(dtlow @ W_dt^T + b_dt)  (4096x64 @ 64x2048) -> f32
    gemm_bt<128, 128, 64, 2><<<dim3(32, 16), 256, 0, stream>>>(
        dtlow, Wdt_bf, dtb, b_dt, 64, DI);
    // 6-8. chunked selective scan (+ D*u, * silu(z)) -> yb bf16
    scan1<<<dim3(DI / 256, BSZ, NCH), 256, 0, stream>>>(
        dtb, u_c, x_dbl, A_log, chunkh, Ssum);
    scan2<<<(BSZ * DI * DS) / 256, 256, 0, stream>>>(chunkh, Ssum, A_log);
    scan3<<<dim3(DI / 256, BSZ, NCH), 256, 0, stream>>>(
        dtb, u_c, x_dbl, A_log, chunkh, Dv, xz, yb);
    // 9. out = yb @ W_out^T + x  (4096x2048 @ 2048x1024) -> f32
    gemm_bt<128, 128, 64, 3><<<dim3(32, 8), 256, 0, stream>>>(
        yb, Wout_bf, out, x, DI, DMODEL);
}

// Round 4
// 212.545 us; speedup vs baseline: 1.8389x; 1.1835x over previous
//
#include <hip/hip_runtime.h>

// ---------- common helpers ----------
typedef __bf16 bf16x8 __attribute__((ext_vector_type(8)));
typedef float  f32x4  __attribute__((ext_vector_type(4)));

#define LOG2E 1.44269504088896f

__device__ __forceinline__ float bfl(unsigned short s) {
    return __uint_as_float(((unsigned int)s) << 16);
}
__device__ __forceinline__ unsigned short f2bf(float f) {  // RNE
    unsigned int x = __float_as_uint(f);
    x += 0x7fffu + ((x >> 16) & 1u);
    return (unsigned short)(x >> 16);
}
__device__ __forceinline__ float fexp2(float x) { return __builtin_amdgcn_exp2f(x); }
__device__ __forceinline__ float fexp(float x)  { return __builtin_amdgcn_exp2f(x * LOG2E); }
__device__ __forceinline__ float frcp(float x)  { return __builtin_amdgcn_rcpf(x); }
__device__ __forceinline__ float silu_f(float x) {
    return x * frcp(1.f + fexp2(-x * LOG2E));
}
__device__ __forceinline__ void gl_lds(const unsigned short* g, unsigned short* l) {
    __builtin_amdgcn_global_load_lds(
        (__attribute__((address_space(1))) const void*)g,
        (__attribute__((address_space(3))) void*)l, 16, 0, 0);
}

// dims
#define BSZ   2
#define LSEQ  2048
#define DMODEL 1024
#define DI    2048
#define DS    16
#define NCH   64        // chunks
#define CL    32        // steps per chunk (LSEQ/NCH)

// ---------- f32 -> bf16 weight conversion (4 concatenated segments) ----------
#define WI_N   4194304          // 2*DI*DMODEL
#define WXP_N  196608           // 96*DI
#define WDT_N  131072           // DI*64
#define WOUT_N 2097152          // DMODEL*DI
#define WSEG1  (WI_N)
#define WSEG2  (WI_N + WXP_N)
#define WSEG3  (WI_N + WXP_N + WDT_N)
#define WTOT   (WI_N + WXP_N + WDT_N + WOUT_N)   // 6,619,136

__global__ __launch_bounds__(256) void cvt_weights(
    const float* __restrict__ w0, const float* __restrict__ w1,
    const float* __restrict__ w2, const float* __restrict__ w3,
    unsigned short* __restrict__ dst)
{
    const size_t e0 = ((size_t)blockIdx.x * 256 + threadIdx.x) * 8;
    if (e0 >= WTOT) return;
    const float* src;
    size_t off;
    if      (e0 < WSEG1) { src = w0; off = e0; }
    else if (e0 < WSEG2) { src = w1; off = e0 - WSEG1; }
    else if (e0 < WSEG3) { src = w2; off = e0 - WSEG2; }
    else                 { src = w3; off = e0 - WSEG3; }
    float4 a = *(const float4*)(src + off);
    float4 b = *(const float4*)(src + off + 4);
    ushort4 lo, hi;
    lo.x = f2bf(a.x); lo.y = f2bf(a.y); lo.z = f2bf(a.z); lo.w = f2bf(a.w);
    hi.x = f2bf(b.x); hi.y = f2bf(b.y); hi.z = f2bf(b.z); hi.w = f2bf(b.w);
    *(ushort4*)(dst + e0) = lo;
    *(ushort4*)(dst + e0 + 4) = hi;
}

// ---------- LayerNorm (f32 in -> bf16 out) ----------
__global__ __launch_bounds__(256) void ln_kernel(
    const float* __restrict__ x,
    const float* __restrict__ g,
    const float* __restrict__ b,
    unsigned short* __restrict__ xn)
{
    const int row = blockIdx.x;
    const int tid = threadIdx.x;
    const int lane = tid & 63, wv = tid >> 6;
    const float* xp = x + (size_t)row * DMODEL;

    float4 v = ((const float4*)xp)[tid];
    float s = v.x + v.y + v.z + v.w;
    float q = v.x*v.x + v.y*v.y + v.z*v.z + v.w*v.w;
    #pragma unroll
    for (int o = 32; o > 0; o >>= 1) {
        s += __shfl_down(s, o);
        q += __shfl_down(q, o);
    }
    __shared__ float ss[4], sq[4];
    if (lane == 0) { ss[wv] = s; sq[wv] = q; }
    __syncthreads();
    s = ss[0] + ss[1] + ss[2] + ss[3];
    q = sq[0] + sq[1] + sq[2] + sq[3];
    const float mu  = s * (1.f / DMODEL);
    const float var = q * (1.f / DMODEL) - mu * mu;
    const float rs  = rsqrtf(var + 1e-5f);

    float4 gv = ((const float4*)g)[tid];
    float4 bv = ((const float4*)b)[tid];
    ushort4 o;
    o.x = f2bf((v.x - mu) * rs * gv.x + bv.x);
    o.y = f2bf((v.y - mu) * rs * gv.y + bv.y);
    o.z = f2bf((v.z - mu) * rs * gv.z + bv.z);
    o.w = f2bf((v.w - mu) * rs * gv.w + bv.w);
    ((ushort4*)(xn + (size_t)row * DMODEL))[tid] = o;
}

// ---------- 128x128 GEMM, global_load_lds staging (m97 structure) ----------
// C[M,N] = A[M,K] * B[N,K]^T, bf16 operands, BK=64, linear LDS.
// EPI 0: store bf16 (ldc)
// EPI 2: v = softplus(v + f32 aux0[col]); store bf16
// EPI 3: v += f32 aux0[row*ldc+col]; store f32 (residual add)
template<int EPI>
__global__ __launch_bounds__(256) void gemm_lds(
    const unsigned short* __restrict__ A,
    const unsigned short* __restrict__ Bw,
    void* __restrict__ Cout,
    const void* __restrict__ aux0,
    int K, int ldc)
{
    __shared__ unsigned short As[128 * 64];
    __shared__ unsigned short Bs[128 * 64];
    const int tid  = threadIdx.x;
    const int lane = tid & 63;
    const int wv   = tid >> 6;
    const int wm   = (wv >> 1) * 64;
    const int wn   = (wv & 1)  * 64;

    f32x4 acc[4][4];
    f32x4 z4 = {0.f, 0.f, 0.f, 0.f};
    #pragma unroll
    for (int i = 0; i < 4; ++i)
        #pragma unroll
        for (int j = 0; j < 4; ++j) acc[i][j] = z4;

    const size_t am0 = (size_t)blockIdx.x * 128;
    const size_t bn0 = (size_t)blockIdx.y * 128;
    const int srow  = lane >> 3;          // 0..7
    const int scol  = (lane & 7) * 8;     // 0..56
    const int sbase = wv * 4 * 512;       // ushort idx of this wave's first issue

    for (int k0 = 0; k0 < K; k0 += 64) {
        __syncthreads();
        #pragma unroll
        for (int i = 0; i < 4; ++i) {
            const int rr = (wv * 4 + i) * 8 + srow;        // 0..127
            gl_lds(&A [(am0 + rr) * (size_t)K + k0 + scol], &As[sbase + i * 512]);
            gl_lds(&Bw[(bn0 + rr) * (size_t)K + k0 + scol], &Bs[sbase + i * 512]);
        }
        __syncthreads();
        const int lr = lane & 15, lk = (lane >> 4) * 8;
        #pragma unroll
        for (int ks = 0; ks < 2; ++ks) {
            bf16x8 af[4], bfv[4];
            #pragma unroll
            for (int fm = 0; fm < 4; ++fm)
                af[fm] = *(const bf16x8*)&As[(wm + fm * 16 + lr) * 64 + ks * 32 + lk];
            #pragma unroll
            for (int fn = 0; fn < 4; ++fn)
                bfv[fn] = *(const bf16x8*)&Bs[(wn + fn * 16 + lr) * 64 + ks * 32 + lk];
            #pragma unroll
            for (int fm = 0; fm < 4; ++fm)
                #pragma unroll
                for (int fn = 0; fn < 4; ++fn)
                    acc[fm][fn] = __builtin_amdgcn_mfma_f32_16x16x32_bf16(
                        af[fm], bfv[fn], acc[fm][fn], 0, 0, 0);
        }
    }

    const int er = (lane >> 4) * 4;
    const int ec = lane & 15;
    #pragma unroll
    for (int fm = 0; fm < 4; ++fm) {
        #pragma unroll
        for (int fn = 0; fn < 4; ++fn) {
            const size_t col = bn0 + wn + fn * 16 + ec;
            #pragma unroll
            for (int r = 0; r < 4; ++r) {
                const size_t row = am0 + wm + fm * 16 + er + r;
                float v = acc[fm][fn][r];
                if constexpr (EPI == 0) {
                    ((unsigned short*)Cout)[row * ldc + col] = f2bf(v);
                } else if constexpr (EPI == 2) {
                    float t = v + ((const float*)aux0)[col];
                    float e = fexp2(t * LOG2E);
                    float sp = 0.69314718056f * __builtin_amdgcn_logf(1.f + e);
                    if (t > 20.f) sp = t;
                    ((unsigned short*)Cout)[row * ldc + col] = f2bf(sp);
                } else {
                    float t = v + ((const float*)aux0)[row * ldc + col];
                    ((float*)Cout)[row * ldc + col] = t;
                }
            }
        }
    }
}

// ---------- GEMM4 split-K: Cpart[kz] = A[:,kz-slice] * B[:,kz-slice]^T ----------
// M=4096, N=96, K=2048, SPLITK=8 -> each block: 64x96 tile over K=256
__global__ __launch_bounds__(256) void gemm4_splitk(
    const unsigned short* __restrict__ A,    // (4096, 2048) bf16
    const unsigned short* __restrict__ Bw,   // (96, 2048) bf16
    float* __restrict__ Cpart)               // (8, 4096, 96) f32
{
    constexpr int LDP = 72;
    __shared__ unsigned short As[64 * LDP];
    __shared__ unsigned short Bs[96 * LDP];
    const int tid  = threadIdx.x;
    const int lane = tid & 63;
    const int wv   = tid >> 6;
    const int wm   = (wv >> 1) * 32;
    const int wn   = (wv & 1)  * 48;

    f32x4 acc[2][3];
    f32x4 z4 = {0.f, 0.f, 0.f, 0.f};
    #pragma unroll
    for (int i = 0; i < 2; ++i)
        #pragma unroll
        for (int j = 0; j < 3; ++j) acc[i][j] = z4;

    const size_t am0 = (size_t)blockIdx.x * 64;
    const int kz = blockIdx.y;
    const int kbeg = kz * 256;
    const int r0 = tid >> 3;
    const int c0 = (tid & 7) * 8;

    for (int k0 = kbeg; k0 < kbeg + 256; k0 += 64) {
        __syncthreads();
        #pragma unroll
        for (int p = 0; p < 2; ++p) {
            int r = r0 + p * 32;
            *(uint4*)&As[r * LDP + c0] = *(const uint4*)&A[(am0 + r) * (size_t)2048 + k0 + c0];
        }
        #pragma unroll
        for (int p = 0; p < 3; ++p) {
            int r = r0 + p * 32;
            *(uint4*)&Bs[r * LDP + c0] = *(const uint4*)&Bw[(size_t)r * 2048 + k0 + c0];
        }
        __syncthreads();
        const int lr = lane & 15, lk = (lane >> 4) * 8;
        #pragma unroll
        for (int ks = 0; ks < 2; ++ks) {
            bf16x8 af[2], bfv[3];
            #pragma unroll
            for (int fm = 0; fm < 2; ++fm)
                af[fm] = *(const bf16x8*)&As[(wm + fm * 16 + lr) * LDP + ks * 32 + lk];
            #pragma unroll
            for (int fn = 0; fn < 3; ++fn)
                bfv[fn] = *(const bf16x8*)&Bs[(wn + fn * 16 + lr) * LDP + ks * 32 + lk];
            #pragma unroll
            for (int fm = 0; fm < 2; ++fm)
                #pragma unroll
                for (int fn = 0; fn < 3; ++fn)
                    acc[fm][fn] = __builtin_amdgcn_mfma_f32_16x16x32_bf16(
                        af[fm], bfv[fn], acc[fm][fn], 0, 0, 0);
        }
    }

    const int er = (lane >> 4) * 4;
    const int ec = lane & 15;
    float* out = Cpart + (size_t)kz * 4096 * 96;
    #pragma unroll
    for (int fm = 0; fm < 2; ++fm) {
        #pragma unroll
        for (int fn = 0; fn < 3; ++fn) {
            const int col = wn + fn * 16 + ec;
            #pragma unroll
            for (int r = 0; r < 4; ++r) {
                const size_t row = am0 + wm + fm * 16 + er + r;
                out[row * 96 + col] = acc[fm][fn][r];
            }
        }
    }
}

// ---------- reduce split-K partials -> x_dbl f32 + dtlow bf16 ----------
__global__ __launch_bounds__(256) void reduce_xdbl(
    const float* __restrict__ Cpart,     // (8, 4096, 96)
    float* __restrict__ x_dbl,           // (4096, 96)
    unsigned short* __restrict__ dtlow)  // (4096, 64) bf16
{
    const int e = blockIdx.x * 256 + threadIdx.x;   // < 393216
    float s = 0.f;
    #pragma unroll
    for (int kz = 0; kz < 8; ++kz) s += Cpart[(size_t)kz * 393216 + e];
    x_dbl[e] = s;
    const int row = e / 96, col = e - row * 96;
    if (col < 64) dtlow[row * 64 + col] = f2bf(s);
}

// ---------- causal depthwise conv (window 4) + bias + SiLU ----------
__global__ __launch_bounds__(256) void conv_silu(
    const unsigned short* __restrict__ xz,     // (B*L, 2*DI) bf16, u = cols [0,DI)
    const float* __restrict__ convw,           // (DI,4) f32
    const float* __restrict__ convb,           // (DI,) f32
    unsigned short* __restrict__ u_c)          // (B*L, DI) bf16
{
    const size_t i = (size_t)blockIdx.x * 256 + threadIdx.x;
    if (i >= (size_t)BSZ * LSEQ * DI) return;
    const int d = (int)(i & (DI - 1));
    const size_t bl = i >> 11;            // b*L + l
    const int l = (int)(bl & (LSEQ - 1));
    const int b = (int)(bl >> 11);

    float4 wv = *(const float4*)&convw[d * 4];
    float acc = convb[d];
    const size_t rowbase = (size_t)(b * LSEQ) * (2 * DI) + d;
    if (l >= 3) acc += bfl(xz[rowbase + (size_t)(l - 3) * (2 * DI)]) * wv.x;
    if (l >= 2) acc += bfl(xz[rowbase + (size_t)(l - 2) * (2 * DI)]) * wv.y;
    if (l >= 1) acc += bfl(xz[rowbase + (size_t)(l - 1) * (2 * DI)]) * wv.z;
    acc += bfl(xz[rowbase + (size_t)l * (2 * DI)]) * wv.w;
    u_c[i] = f2bf(silu_f(acc));
}

// ---------- A-row load: An2[n] = -exp(A_log[d][n]) * log2(e); fast = S4D ----------
__device__ __forceinline__ bool load_A(const float* __restrict__ A_log, int d, float* An2) {
    bool fast = true;
    #pragma unroll
    for (int i = 0; i < 4; ++i) {
        float4 a = *(const float4*)&A_log[(size_t)d * DS + i * 4];
        float e0 = fexp(a.x), e1 = fexp(a.y), e2 = fexp(a.z), e3 = fexp(a.w);
        fast = fast && fabsf(e0 - (4*i+1)) < 1e-3f * (4*i+1)
                    && fabsf(e1 - (4*i+2)) < 1e-3f * (4*i+2)
                    && fabsf(e2 - (4*i+3)) < 1e-3f * (4*i+3)
                    && fabsf(e3 - (4*i+4)) < 1e-3f * (4*i+4);
        An2[4*i+0] = -e0 * LOG2E; An2[4*i+1] = -e1 * LOG2E;
        An2[4*i+2] = -e2 * LOG2E; An2[4*i+3] = -e3 * LOG2E;
    }
    return fast;
}

// ---------- selective scan, pass 1: per-chunk local scan (h_in = 0) ----------
__global__ __launch_bounds__(256) void scan1(
    const unsigned short* __restrict__ dt,  // (B*L, DI) bf16
    const unsigned short* __restrict__ u_c, // (B*L, DI) bf16
    const float* __restrict__ x_dbl,        // (B*L, 96) f32; B = cols 64..79
    const float* __restrict__ A_log,        // (DI,16) f32
    float* __restrict__ chunk_h,            // [b][c][d][16] f32
    float* __restrict__ Ssum)               // [b][c][d] f32
{
    const int d = blockIdx.x * 256 + threadIdx.x;
    const int b = blockIdx.y, c = blockIdx.z;
    const int tid = threadIdx.x;

    __shared__ float sB[CL][DS];
    if (tid < 128) {
        int s = tid >> 2, j = (tid & 3) * 4;
        *(float4*)&sB[s][j] =
            *(const float4*)&x_dbl[(size_t)(b * LSEQ + c * CL + s) * 96 + 64 + j];
    }

    float An2[DS];
    const bool fast = load_A(A_log, d, An2);
    __syncthreads();

    float h[DS];
    #pragma unroll
    for (int n = 0; n < DS; ++n) h[n] = 0.f;
    float S = 0.f;
    const size_t base = (size_t)(b * LSEQ + c * CL) * DI + d;
    if (fast) {
        for (int s = 0; s < CL; ++s) {
            float dtt = bfl(dt[base + (size_t)s * DI]);
            float ut  = bfl(u_c[base + (size_t)s * DI]);
            S += dtt;
            float dtu = dtt * ut;
            float e1 = fexp2(-dtt * LOG2E);   // exp(-dt); dA[n] = e1^(n+1)
            float p = 1.f;
            #pragma unroll
            for (int n = 0; n < DS; ++n) {
                p *= e1;
                h[n] = p * h[n] + dtu * sB[s][n];
            }
        }
    } else {
        for (int s = 0; s < CL; ++s) {
            float dtt = bfl(dt[base + (size_t)s * DI]);
            float ut  = bfl(u_c[base + (size_t)s * DI]);
            S += dtt;
            float dtu = dtt * ut;
            #pragma unroll
            for (int n = 0; n < DS; ++n) {
                float dA = fexp2(dtt * An2[n]);
                h[n] = dA * h[n] + dtu * sB[s][n];
            }
        }
    }
    const size_t co = ((size_t)((b * NCH + c) * DI) + d) * DS;
    #pragma unroll
    for (int n = 0; n < DS; ++n) chunk_h[co + n] = h[n];
    Ssum[(size_t)(b * NCH + c) * DI + d] = S;
}

// ---------- scan pass 2: combine chunks; overwrite chunk_h with per-chunk h_in ----------
__global__ __launch_bounds__(256) void scan2(
    float* __restrict__ chunk_h,
    const float* __restrict__ Ssum,
    const float* __restrict__ A_log)
{
    const int gid = blockIdx.x * 256 + threadIdx.x;   // (b,d,n)
    const int b = gid >> 15;
    const int rem = gid & 32767;
    const int d = rem >> 4;
    const int n = rem & 15;
    const float A2 = -fexp(A_log[(size_t)d * DS + n]) * LOG2E;
    float H = 0.f;
    for (int c = 0; c < NCH; ++c) {
        const size_t idx = ((size_t)((b * NCH + c) * DI) + d) * DS + n;
        float hl = chunk_h[idx];
        float S  = Ssum[(size_t)(b * NCH + c) * DI + d];
        chunk_h[idx] = H;                 // start state for chunk c
        H = fexp2(A2 * S) * H + hl;
    }
}

// ---------- scan pass 3: full scan with h_in + y = (h.C + D*u) * silu(z) ----------
__global__ __launch_bounds__(256) void scan3(
    const unsigned short* __restrict__ dt,
    const unsigned short* __restrict__ u_c,
    const float* __restrict__ x_dbl,          // B = 64..79, C = 80..95
    const float* __restrict__ A_log,
    const float* __restrict__ Hstart,
    const float* __restrict__ Dvec,           // (DI,) f32
    const unsigned short* __restrict__ xz,    // z = cols [DI, 2*DI) bf16
    unsigned short* __restrict__ yb)          // (B*L, DI) bf16
{
    const int d = blockIdx.x * 256 + threadIdx.x;
    const int b = blockIdx.y, c = blockIdx.z;
    const int tid = threadIdx.x;

    __shared__ float sBC[CL][32];
    {
        int s = tid >> 3, j = (tid & 7) * 4;
        *(float4*)&sBC[s][j] =
            *(const float4*)&x_dbl[(size_t)(b * LSEQ + c * CL + s) * 96 + 64 + j];
    }

    float An2[DS];
    const bool fast = load_A(A_log, d, An2);
    const float Dd = Dvec[d];
    float h[DS];
    const size_t co = ((size_t)((b * NCH + c) * DI) + d) * DS;
    #pragma unroll
    for (int n = 0; n < DS; ++n) h[n] = Hstart[co + n];
    __syncthreads();

    const size_t base  = (size_t)(b * LSEQ + c * CL) * DI + d;
    const size_t zbase = (size_t)(b * LSEQ + c * CL) * (2 * DI) + DI + d;
    if (fast) {
        for (int s = 0; s < CL; ++s) {
            float dtt = bfl(dt[base + (size_t)s * DI]);
            float ut  = bfl(u_c[base + (size_t)s * DI]);
            float dtu = dtt * ut;
            float e1 = fexp2(-dtt * LOG2E);
            float p = 1.f;
            float a0 = 0.f, a1 = 0.f;
            #pragma unroll
            for (int n = 0; n < DS; ++n) {
                p *= e1;
                h[n] = p * h[n] + dtu * sBC[s][n];
                if (n & 1) a1 += h[n] * sBC[s][16 + n];
                else       a0 += h[n] * sBC[s][16 + n];
            }
            float y = a0 + a1 + Dd * ut;
            float z = bfl(xz[zbase + (size_t)s * (2 * DI)]);
            yb[base + (size_t)s * DI] = f2bf(y * silu_f(z));
        }
    } else {
        for (int s = 0; s < CL; ++s) {
            float dtt = bfl(dt[base + (size_t)s * DI]);
            float ut  = bfl(u_c[base + (size_t)s * DI]);
            float dtu = dtt * ut;
            float a0 = 0.f, a1 = 0.f;
            #pragma unroll
            for (int n = 0; n < DS; ++n) {
                float dA = fexp2(dtt * An2[n]);
                h[n] = dA * h[n] + dtu * sBC[s][n];
                if (n & 1) a1 += h[n] * sBC[s][16 + n];
                else       a0 += h[n] * sBC[s][16 + n];
            }
            float y = a0 + a1 + Dd * ut;
            float z = bfl(xz[zbase + (size_t)s * (2 * DI)]);
            yb[base + (size_t)s * DI] = f2bf(y * silu_f(z));
        }
    }
}

// ---------- host launcher ----------
extern "C" void kernel_launch(void* const* d_in, const int* in_sizes, int n_in,
                              void* d_out, int out_size, void* d_ws, size_t ws_size,
                              hipStream_t stream) {
    const float* x      = (const float*)d_in[0];
    const float* ln_g   = (const float*)d_in[1];
    const float* ln_b   = (const float*)d_in[2];
    const float* W_in   = (const float*)d_in[3];
    const float* conv_w = (const float*)d_in[4];
    const float* conv_b = (const float*)d_in[5];
    const float* W_xp   = (const float*)d_in[6];
    const float* W_dt   = (const float*)d_in[7];
    const float* b_dt   = (const float*)d_in[8];
    const float* A_log  = (const float*)d_in[9];
    const float* Dv     = (const float*)d_in[10];
    const float* W_out  = (const float*)d_in[11];
    float* out = (float*)d_out;

    char* w = (char*)d_ws;
    unsigned short* xn     = (unsigned short*)(w + 0);           //  8,388,608
    unsigned short* xz     = (unsigned short*)(w + 8388608);     // 33,554,432
    unsigned short* u_c    = (unsigned short*)(w + 41943040);    // 16,777,216
    float*          x_dbl  = (float*)         (w + 58720256);    //  1,572,864
    unsigned short* dtlow  = (unsigned short*)(w + 60293120);    //    524,288
    unsigned short* dtb    = (unsigned short*)(w + 60817408);    // 16,777,216 (bf16 now)
    float*          chunkh = (float*)         (w + 77594624);    // 16,777,216
    float*          Ssum   = (float*)         (w + 94371840);    //  1,048,576
    unsigned short* yb     = (unsigned short*)(w + 95420416);    // 16,777,216
    unsigned short* wbf    = (unsigned short*)(w + 112197632);   // 13,238,272
    float*          Cpart  = (float*)         (w + 125435904);   // 12,582,912 (end 138,018,816)
    unsigned short* Wi_bf   = wbf;
    unsigned short* Wxp_bf  = wbf + WSEG1;
    unsigned short* Wdt_bf  = wbf + WSEG2;
    unsigned short* Wout_bf = wbf + WSEG3;
    (void)in_sizes; (void)n_in; (void)out_size; (void)ws_size;

    const int MROWS = BSZ * LSEQ;  // 4096

    // 0. weights f32 -> bf16
    cvt_weights<<<(WTOT / 8 + 255) / 256, 256, 0, stream>>>(
        W_in, W_xp, W_dt, W_out, wbf);
    // 1. LayerNorm (f32 -> bf16)
    ln_kernel<<<MROWS, 256, 0, stream>>>(x, ln_g, ln_b, xn);
    // 2. xz = xn @ W_in^T  (4096x1024 @ 1024x4096) -> bf16
    gemm_lds<0><<<dim3(32, 32), 256, 0, stream>>>(
        xn, Wi_bf, xz, nullptr, DMODEL, 2 * DI);
    // 3. causal conv + SiLU -> bf16
    conv_silu<<<(MROWS * DI) / 256, 256, 0, stream>>>(xz, conv_w, conv_b, u_c);
    // 4. x_dbl = u_c @ W_xp^T  (4096x2048 @ 2048x96), split-K + reduce
    gemm4_splitk<<<dim3(64, 8), 256, 0, stream>>>(u_c, Wxp_bf, Cpart);
    reduce_xdbl<<<(MROWS * 96) / 256, 256, 0, stream>>>(Cpart, x_dbl, dtlow);
    // 5. dt = softplus(dtlow @ W_dt^T + b_dt)  (4096x64 @ 64x2048) -> bf16
    gemm_lds<2><<<dim3(32, 16), 256, 0, stream>>>(
        dtlow, Wdt_bf, dtb, b_dt, 64, DI);
    // 6-8. chunked selective scan (+ D*u, * silu(z)) -> yb bf16
    scan1<<<dim3(DI / 256, BSZ, NCH), 256, 0, stream>>>(
        dtb, u_c, x_dbl, A_log, chunkh, Ssum);
    scan2<<<(BSZ * DI * DS) / 256, 256, 0, stream>>>(chunkh, Ssum, A_log);
    scan3<<<dim3(DI / 256, BSZ, NCH), 256, 0, stream>>>(
        dtb, u_c, x_dbl, A_log, chunkh, Dv, xz, yb);
    // 9. out = yb @ W_out^T + x  (4096x2048 @ 2048x1024) -> f32
    gemm_lds<3><<<dim3(32, 8), 256, 0, stream>>>(
        yb, Wout_bf, out, x, DI, DMODEL);
}